// Round 2
// baseline (3336.592 us; speedup 1.0000x reference)
//
#include <hip/hip_runtime.h>
#include <math.h>

#define NQ 14
#define NL 6
#define NTHREADS 256
#define NGATES (NL * NQ)

using F4 = float4;

// ---- prep: Rot matrices (batch-shared) into d_ws ----
// Rot(phi,theta,omega) = RZ(omega) RY(theta) RZ(phi):
//   m00 =  c e^{-i(phi+om)/2}; m01 = -s e^{+i(phi-om)/2}
//   m10 =  s e^{-i(phi-om)/2}; m11 =  c e^{+i(phi+om)/2}
__global__ void prep_kernel(const float* __restrict__ wts, float* __restrict__ gm) {
    int g = blockIdx.x * blockDim.x + threadIdx.x;
    if (g < NGATES) {
        float phi = wts[g*3+0], th = wts[g*3+1], om = wts[g*3+2];
        float c = cosf(0.5f*th), s = sinf(0.5f*th);
        float a = 0.5f*(phi+om), bb = 0.5f*(phi-om);
        float ca = cosf(a), sa = sinf(a);
        float cb = cosf(bb), sb = sinf(bb);
        gm[g*8+0] = c*ca;  gm[g*8+1] = -c*sa;
        gm[g*8+2] = -s*cb; gm[g*8+3] = -s*sb;
        gm[g*8+4] = s*cb;  gm[g*8+5] = -s*sb;
        gm[g*8+6] = c*ca;  gm[g*8+7] = c*sa;
    }
}

// State: thread `tid` holds amps with global index (tid<<6)|j, j=0..63.
// Amp bit p: p<6 local (register), 6<=p<12 lane bit (shuffle), p>=12 wave bit (LDS).
// Wire w <-> amp bit P = 13-w.

// ---- RX(t): [[c,-is],[-is,c]] (symmetric: same combine for lo and hi) ----
template<int P>
__device__ __forceinline__ void rx_gate(float (&ar)[64], float (&ai)[64],
                                        float c, float s, int tid, F4* buf) {
    if constexpr (P < 6) {
        constexpr int M = 1 << P;
        #pragma unroll
        for (int i = 0; i < 32; ++i) {
            int j0 = ((i >> P) << (P+1)) | (i & (M-1));
            int j1 = j0 | M;
            float r0=ar[j0], i0=ai[j0], r1=ar[j1], i1=ai[j1];
            ar[j0] = c*r0 + s*i1;
            ai[j0] = c*i0 - s*r1;
            ar[j1] = s*i0 + c*r1;
            ai[j1] = -s*r0 + c*i1;
        }
    } else if constexpr (P < 12) {
        constexpr int LM = 1 << (P-6);
        #pragma unroll
        for (int j = 0; j < 64; ++j) {
            float br = __shfl_xor(ar[j], LM, 64);
            float bi = __shfl_xor(ai[j], LM, 64);
            float nr = c*ar[j] + s*bi;
            float ni = c*ai[j] - s*br;
            ar[j] = nr; ai[j] = ni;
        }
    } else {
        constexpr int WM = 1 << (P-6);
        int ptid = tid ^ WM;
        #pragma unroll
        for (int h = 0; h < 2; ++h) {
            int base = h*32;
            #pragma unroll
            for (int k = 0; k < 8; ++k) {
                int j = base + 4*k;
                buf[k*256 + tid]     = make_float4(ar[j],ar[j+1],ar[j+2],ar[j+3]);
                buf[(k+8)*256 + tid] = make_float4(ai[j],ai[j+1],ai[j+2],ai[j+3]);
            }
            __syncthreads();
            #pragma unroll
            for (int k = 0; k < 8; ++k) {
                F4 pr = buf[k*256 + ptid];
                F4 pi = buf[(k+8)*256 + ptid];
                int j = base + 4*k;
                float prx[4] = {pr.x,pr.y,pr.z,pr.w};
                float pix[4] = {pi.x,pi.y,pi.z,pi.w};
                #pragma unroll
                for (int m = 0; m < 4; ++m) {
                    float nr = c*ar[j+m] + s*pix[m];
                    float ni = c*ai[j+m] - s*prx[m];
                    ar[j+m] = nr; ai[j+m] = ni;
                }
            }
            __syncthreads();
        }
    }
}

// ---- Rot: general 2x2 complex. lo' = m00*lo + m01*hi; hi' = m10*lo + m11*hi ----
template<int P>
__device__ __forceinline__ void rot_gate(float (&ar)[64], float (&ai)[64],
                                         const float* __restrict__ m, int tid, F4* buf) {
    if constexpr (P < 6) {
        constexpr int M = 1 << P;
        float m0=m[0],m1=m[1],m2=m[2],m3=m[3],m4=m[4],m5=m[5],m6=m[6],m7=m[7];
        #pragma unroll
        for (int i = 0; i < 32; ++i) {
            int j0 = ((i >> P) << (P+1)) | (i & (M-1));
            int j1 = j0 | M;
            float r0=ar[j0], i0=ai[j0], r1=ar[j1], i1=ai[j1];
            ar[j0] = m0*r0 - m1*i0 + m2*r1 - m3*i1;
            ai[j0] = m0*i0 + m1*r0 + m2*i1 + m3*r1;
            ar[j1] = m4*r0 - m5*i0 + m6*r1 - m7*i1;
            ai[j1] = m4*i0 + m5*r0 + m6*i1 + m7*r1;
        }
    } else if constexpr (P < 12) {
        constexpr int LM = 1 << (P-6);
        int bit = (tid >> (P-6)) & 1;
        // bit==0: own=lo -> out = m00*own + m01*partner
        // bit==1: own=hi -> out = m11*own + m10*partner
        float cAr = bit ? m[6] : m[0];
        float cAi = bit ? m[7] : m[1];
        float cBr = bit ? m[4] : m[2];
        float cBi = bit ? m[5] : m[3];
        #pragma unroll
        for (int j = 0; j < 64; ++j) {
            float br = __shfl_xor(ar[j], LM, 64);
            float bi = __shfl_xor(ai[j], LM, 64);
            float nr = cAr*ar[j] - cAi*ai[j] + cBr*br - cBi*bi;
            float ni = cAr*ai[j] + cAi*ar[j] + cBr*bi + cBi*br;
            ar[j] = nr; ai[j] = ni;
        }
    } else {
        constexpr int WM = 1 << (P-6);
        int ptid = tid ^ WM;
        int bit = (tid >> (P-6)) & 1;
        float cAr = bit ? m[6] : m[0];
        float cAi = bit ? m[7] : m[1];
        float cBr = bit ? m[4] : m[2];
        float cBi = bit ? m[5] : m[3];
        #pragma unroll
        for (int h = 0; h < 2; ++h) {
            int base = h*32;
            #pragma unroll
            for (int k = 0; k < 8; ++k) {
                int j = base + 4*k;
                buf[k*256 + tid]     = make_float4(ar[j],ar[j+1],ar[j+2],ar[j+3]);
                buf[(k+8)*256 + tid] = make_float4(ai[j],ai[j+1],ai[j+2],ai[j+3]);
            }
            __syncthreads();
            #pragma unroll
            for (int k = 0; k < 8; ++k) {
                F4 pr = buf[k*256 + ptid];
                F4 pi = buf[(k+8)*256 + ptid];
                int j = base + 4*k;
                float prx[4] = {pr.x,pr.y,pr.z,pr.w};
                float pix[4] = {pi.x,pi.y,pi.z,pi.w};
                #pragma unroll
                for (int m = 0; m < 4; ++m) {
                    float nr = cAr*ar[j+m] - cAi*ai[j+m] + cBr*prx[m] - cBi*pix[m];
                    float ni = cAr*ai[j+m] + cAi*ar[j+m] + cBr*pix[m] + cBi*prx[m];
                    ar[j+m] = nr; ai[j+m] = ni;
                }
            }
            __syncthreads();
        }
    }
}

// ---- CNOT(control bit PC, target bit PT): swap target-pairs where ctrl==1 ----
template<int PC, int PT>
__device__ __forceinline__ void cnot_gate(float (&ar)[64], float (&ai)[64], int tid, F4* buf) {
    if constexpr (PT < 6) {
        constexpr int TM = 1 << PT;
        if constexpr (PC < 6) {
            constexpr int CM = 1 << PC;
            #pragma unroll
            for (int j = 0; j < 64; ++j) {
                if ((j & CM) && !(j & TM)) {
                    int j1 = j | TM;
                    float t = ar[j]; ar[j] = ar[j1]; ar[j1] = t;
                    t = ai[j]; ai[j] = ai[j1]; ai[j1] = t;
                }
            }
        } else {
            int sel = (tid >> (PC-6)) & 1;
            #pragma unroll
            for (int i = 0; i < 32; ++i) {
                int j0 = ((i >> PT) << (PT+1)) | (i & (TM-1));
                int j1 = j0 | TM;
                float a = ar[j0], bv = ar[j1];
                ar[j0] = sel ? bv : a; ar[j1] = sel ? a : bv;
                a = ai[j0]; bv = ai[j1];
                ai[j0] = sel ? bv : a; ai[j1] = sel ? a : bv;
            }
        }
    } else if constexpr (PT < 12) {
        constexpr int LM = 1 << (PT-6);
        if constexpr (PC < 6) {
            constexpr int CM = 1 << PC;
            #pragma unroll
            for (int j = 0; j < 64; ++j) {
                if (j & CM) {
                    ar[j] = __shfl_xor(ar[j], LM, 64);
                    ai[j] = __shfl_xor(ai[j], LM, 64);
                }
            }
        } else {
            int sel = (tid >> (PC-6)) & 1;
            if (sel) {   // partner (differs only in PT bit) has same sel -> active
                #pragma unroll
                for (int j = 0; j < 64; ++j) {
                    ar[j] = __shfl_xor(ar[j], LM, 64);
                    ai[j] = __shfl_xor(ai[j], LM, 64);
                }
            }
        }
    } else {
        constexpr int WM = 1 << (PT-6);
        int ptid = tid ^ WM;
        if constexpr (PC < 6) {
            constexpr int CM = 1 << PC;
            // exchange the 32 ctrl==1 amps with wave-partner; single 64KB round
            #pragma unroll
            for (int k = 0; k < 8; ++k) {
                float v[8];
                #pragma unroll
                for (int m = 0; m < 4; ++m) {
                    int i = 4*k + m;
                    int j = ((i >> PC) << (PC+1)) | (i & (CM-1)) | CM;
                    v[m] = ar[j]; v[4+m] = ai[j];
                }
                buf[k*256+tid]     = make_float4(v[0],v[1],v[2],v[3]);
                buf[(k+8)*256+tid] = make_float4(v[4],v[5],v[6],v[7]);
            }
            __syncthreads();
            #pragma unroll
            for (int k = 0; k < 8; ++k) {
                F4 pr = buf[k*256+ptid];
                F4 pi = buf[(k+8)*256+ptid];
                float prx[4] = {pr.x,pr.y,pr.z,pr.w};
                float pix[4] = {pi.x,pi.y,pi.z,pi.w};
                #pragma unroll
                for (int m = 0; m < 4; ++m) {
                    int i = 4*k + m;
                    int j = ((i >> PC) << (PC+1)) | (i & (CM-1)) | CM;
                    ar[j] = prx[m]; ai[j] = pix[m];
                }
            }
            __syncthreads();
        } else {
            // ctrl is a thread bit (lane or other wave bit): sel==1 threads swap
            // their entire 64 amps with wave-partner (partner has same sel).
            int sel = (tid >> (PC-6)) & 1;
            #pragma unroll
            for (int h = 0; h < 2; ++h) {
                int base = h*32;
                if (sel) {
                    #pragma unroll
                    for (int k = 0; k < 8; ++k) {
                        int j = base + 4*k;
                        buf[k*256+tid]     = make_float4(ar[j],ar[j+1],ar[j+2],ar[j+3]);
                        buf[(k+8)*256+tid] = make_float4(ai[j],ai[j+1],ai[j+2],ai[j+3]);
                    }
                }
                __syncthreads();
                if (sel) {
                    #pragma unroll
                    for (int k = 0; k < 8; ++k) {
                        F4 pr = buf[k*256+ptid];
                        F4 pi = buf[(k+8)*256+ptid];
                        int j = base + 4*k;
                        ar[j]=pr.x; ar[j+1]=pr.y; ar[j+2]=pr.z; ar[j+3]=pr.w;
                        ai[j]=pi.x; ai[j+1]=pi.y; ai[j+2]=pi.z; ai[j+3]=pi.w;
                    }
                }
                __syncthreads();
            }
        }
    }
}

// ---- compile-time circuit drivers ----
template<int W>
__device__ __forceinline__ void do_rx(float (&ar)[64], float (&ai)[64],
                                      const float* __restrict__ xb, int tid, F4* buf) {
    float t = xb[W];
    float c = cosf(0.5f*t), s = sinf(0.5f*t);
    rx_gate<13-W>(ar, ai, c, s, tid, buf);
    if constexpr (W < NQ-1) do_rx<W+1>(ar, ai, xb, tid, buf);
}

template<int L, int W>
__device__ __forceinline__ void do_rots(float (&ar)[64], float (&ai)[64],
                                        const float* __restrict__ gm, int tid, F4* buf) {
    rot_gate<13-W>(ar, ai, gm + (L*NQ + W)*8, tid, buf);
    if constexpr (W < NQ-1) do_rots<L, W+1>(ar, ai, gm, tid, buf);
}

template<int L, int W>
__device__ __forceinline__ void do_cnots(float (&ar)[64], float (&ai)[64], int tid, F4* buf) {
    constexpr int R = (L % (NQ-1)) + 1;
    constexpr int TW = (W + R) % NQ;
    cnot_gate<13-W, 13-TW>(ar, ai, tid, buf);
    if constexpr (W < NQ-1) do_cnots<L, W+1>(ar, ai, tid, buf);
}

template<int L>
__device__ __forceinline__ void do_layer(float (&ar)[64], float (&ai)[64],
                                         const float* __restrict__ gm, int tid, F4* buf) {
    do_rots<L, 0>(ar, ai, gm, tid, buf);
    do_cnots<L, 0>(ar, ai, tid, buf);
    if constexpr (L < NL-1) do_layer<L+1>(ar, ai, gm, tid, buf);
}

__global__ __launch_bounds__(NTHREADS, 2) void qsim_kernel(
    const float* __restrict__ x,
    const float* __restrict__ gm,
    float* __restrict__ out)
{
    extern __shared__ F4 buf[];   // 4096 float4 = 64 KB exchange buffer
    const int tid = threadIdx.x;
    const int b = blockIdx.x;

    float ar[64], ai[64];
    #pragma unroll
    for (int j = 0; j < 64; ++j) { ar[j] = 0.f; ai[j] = 0.f; }
    if (tid == 0) ar[0] = 1.f;

    do_rx<0>(ar, ai, x + b*NQ, tid, buf);
    do_layer<0>(ar, ai, gm, tid, buf);

    // <Z0>: amp bit13 = tid bit 7 -> sign uniform per thread
    float acc = 0.f;
    #pragma unroll
    for (int j = 0; j < 64; ++j) acc += ar[j]*ar[j] + ai[j]*ai[j];
    if (tid & 128) acc = -acc;
    #pragma unroll
    for (int off = 32; off > 0; off >>= 1) acc += __shfl_down(acc, off, 64);
    __syncthreads();
    float* f = (float*)buf;
    if ((tid & 63) == 0) f[tid >> 6] = acc;
    __syncthreads();
    if (tid == 0) out[b] = f[0] + f[1] + f[2] + f[3];
}

extern "C" void kernel_launch(void* const* d_in, const int* in_sizes, int n_in,
                              void* d_out, int out_size, void* d_ws, size_t ws_size,
                              hipStream_t stream) {
    const float* x = (const float*)d_in[0];   // (1024, 14) float32
    const float* w = (const float*)d_in[1];   // (6, 14, 3) float32
    float* out = (float*)d_out;               // (1024,) float32
    float* gm = (float*)d_ws;                 // 84*8 floats of Rot matrices

    prep_kernel<<<1, 128, 0, stream>>>(w, gm);
    qsim_kernel<<<out_size, NTHREADS, 4096*sizeof(F4), stream>>>(x, gm, out);
}

// Round 3
// 1144.367 us; speedup vs baseline: 2.9157x; 2.9157x over previous
//
#include <hip/hip_runtime.h>
#include <math.h>

#define NQ 14
#define NL 6
#define NTHREADS 1024
#define NGATES (NL * NQ)
#define CHUNK 16            // amps per thread: amp = (tid<<4) | j
// amp bit p: p<4 local (register), 4<=p<10 lane bit (tid bit p-4),
//            p>=10 wave bit (tid bit p-4 in 6..9). Wire w <-> bit P = 13-w.

using F4 = float4;

// ---- prep: Rot matrices (batch-shared) into d_ws ----
// Rot(phi,theta,omega) = RZ(omega) RY(theta) RZ(phi)
__global__ void prep_kernel(const float* __restrict__ wts, float* __restrict__ gm) {
    int g = blockIdx.x * blockDim.x + threadIdx.x;
    if (g < NGATES) {
        float phi = wts[g*3+0], th = wts[g*3+1], om = wts[g*3+2];
        float c = cosf(0.5f*th), s = sinf(0.5f*th);
        float a = 0.5f*(phi+om), bb = 0.5f*(phi-om);
        float ca = cosf(a), sa = sinf(a);
        float cb = cosf(bb), sb = sinf(bb);
        gm[g*8+0] = c*ca;  gm[g*8+1] = -c*sa;   // m00
        gm[g*8+2] = -s*cb; gm[g*8+3] = -s*sb;   // m01
        gm[g*8+4] = s*cb;  gm[g*8+5] = -s*sb;   // m10
        gm[g*8+6] = c*ca;  gm[g*8+7] = c*sa;    // m11
    }
}

// ---- RX(t): [[c,-is],[-is,c]] (symmetric combine) ----
template<int P>
__device__ __forceinline__ void rx_gate(float (&ar)[CHUNK], float (&ai)[CHUNK],
                                        float c, float s, int tid, F4* buf) {
    if constexpr (P < 4) {
        constexpr int M = 1 << P;
        #pragma unroll
        for (int i = 0; i < CHUNK/2; ++i) {
            int j0 = ((i >> P) << (P+1)) | (i & (M-1));
            int j1 = j0 | M;
            float r0=ar[j0], i0=ai[j0], r1=ar[j1], i1=ai[j1];
            ar[j0] = c*r0 + s*i1;
            ai[j0] = c*i0 - s*r1;
            ar[j1] = s*i0 + c*r1;
            ai[j1] = -s*r0 + c*i1;
        }
    } else if constexpr (P < 10) {
        constexpr int LM = 1 << (P-4);
        #pragma unroll
        for (int j = 0; j < CHUNK; ++j) {
            float br = __shfl_xor(ar[j], LM, 64);
            float bi = __shfl_xor(ai[j], LM, 64);
            float nr = c*ar[j] + s*bi;
            float ni = c*ai[j] - s*br;
            ar[j] = nr; ai[j] = ni;
        }
    } else {
        constexpr int WM = 1 << (P-4);
        int ptid = tid ^ WM;
        #pragma unroll
        for (int k = 0; k < 4; ++k) {
            int j = 4*k;
            buf[k*NTHREADS + tid]     = make_float4(ar[j],ar[j+1],ar[j+2],ar[j+3]);
            buf[(k+4)*NTHREADS + tid] = make_float4(ai[j],ai[j+1],ai[j+2],ai[j+3]);
        }
        __syncthreads();
        #pragma unroll
        for (int k = 0; k < 4; ++k) {
            F4 pr = buf[k*NTHREADS + ptid];
            F4 pi = buf[(k+4)*NTHREADS + ptid];
            int j = 4*k;
            float prx[4] = {pr.x,pr.y,pr.z,pr.w};
            float pix[4] = {pi.x,pi.y,pi.z,pi.w};
            #pragma unroll
            for (int m = 0; m < 4; ++m) {
                float nr = c*ar[j+m] + s*pix[m];
                float ni = c*ai[j+m] - s*prx[m];
                ar[j+m] = nr; ai[j+m] = ni;
            }
        }
        __syncthreads();
    }
}

// ---- Rot: lo' = m00*lo + m01*hi; hi' = m10*lo + m11*hi ----
template<int P>
__device__ __forceinline__ void rot_gate(float (&ar)[CHUNK], float (&ai)[CHUNK],
                                         const float* __restrict__ m, int tid, F4* buf) {
    if constexpr (P < 4) {
        constexpr int M = 1 << P;
        float m0=m[0],m1=m[1],m2=m[2],m3=m[3],m4=m[4],m5=m[5],m6=m[6],m7=m[7];
        #pragma unroll
        for (int i = 0; i < CHUNK/2; ++i) {
            int j0 = ((i >> P) << (P+1)) | (i & (M-1));
            int j1 = j0 | M;
            float r0=ar[j0], i0=ai[j0], r1=ar[j1], i1=ai[j1];
            ar[j0] = m0*r0 - m1*i0 + m2*r1 - m3*i1;
            ai[j0] = m0*i0 + m1*r0 + m2*i1 + m3*r1;
            ar[j1] = m4*r0 - m5*i0 + m6*r1 - m7*i1;
            ai[j1] = m4*i0 + m5*r0 + m6*i1 + m7*r1;
        }
    } else if constexpr (P < 10) {
        constexpr int LM = 1 << (P-4);
        int bit = (tid >> (P-4)) & 1;
        float cAr = bit ? m[6] : m[0];
        float cAi = bit ? m[7] : m[1];
        float cBr = bit ? m[4] : m[2];
        float cBi = bit ? m[5] : m[3];
        #pragma unroll
        for (int j = 0; j < CHUNK; ++j) {
            float br = __shfl_xor(ar[j], LM, 64);
            float bi = __shfl_xor(ai[j], LM, 64);
            float nr = cAr*ar[j] - cAi*ai[j] + cBr*br - cBi*bi;
            float ni = cAr*ai[j] + cAi*ar[j] + cBr*bi + cBi*br;
            ar[j] = nr; ai[j] = ni;
        }
    } else {
        constexpr int WM = 1 << (P-4);
        int ptid = tid ^ WM;
        int bit = (tid >> (P-4)) & 1;
        float cAr = bit ? m[6] : m[0];
        float cAi = bit ? m[7] : m[1];
        float cBr = bit ? m[4] : m[2];
        float cBi = bit ? m[5] : m[3];
        #pragma unroll
        for (int k = 0; k < 4; ++k) {
            int j = 4*k;
            buf[k*NTHREADS + tid]     = make_float4(ar[j],ar[j+1],ar[j+2],ar[j+3]);
            buf[(k+4)*NTHREADS + tid] = make_float4(ai[j],ai[j+1],ai[j+2],ai[j+3]);
        }
        __syncthreads();
        #pragma unroll
        for (int k = 0; k < 4; ++k) {
            F4 pr = buf[k*NTHREADS + ptid];
            F4 pi = buf[(k+4)*NTHREADS + ptid];
            int j = 4*k;
            float prx[4] = {pr.x,pr.y,pr.z,pr.w};
            float pix[4] = {pi.x,pi.y,pi.z,pi.w};
            #pragma unroll
            for (int m = 0; m < 4; ++m) {
                float nr = cAr*ar[j+m] - cAi*ai[j+m] + cBr*prx[m] - cBi*pix[m];
                float ni = cAr*ai[j+m] + cAi*ar[j+m] + cBr*pix[m] + cBi*prx[m];
                ar[j+m] = nr; ai[j+m] = ni;
            }
        }
        __syncthreads();
    }
}

// ---- CNOT(ctrl bit PC, target bit PT) ----
template<int PC, int PT>
__device__ __forceinline__ void cnot_gate(float (&ar)[CHUNK], float (&ai)[CHUNK],
                                          int tid, F4* buf) {
    if constexpr (PT < 4) {
        constexpr int TM = 1 << PT;
        if constexpr (PC < 4) {
            constexpr int CM = 1 << PC;
            #pragma unroll
            for (int j = 0; j < CHUNK; ++j) {
                if ((j & CM) && !(j & TM)) {
                    int j1 = j | TM;
                    float t = ar[j]; ar[j] = ar[j1]; ar[j1] = t;
                    t = ai[j]; ai[j] = ai[j1]; ai[j1] = t;
                }
            }
        } else {
            int sel = (tid >> (PC-4)) & 1;
            #pragma unroll
            for (int i = 0; i < CHUNK/2; ++i) {
                int j0 = ((i >> PT) << (PT+1)) | (i & (TM-1));
                int j1 = j0 | TM;
                float a = ar[j0], bv = ar[j1];
                ar[j0] = sel ? bv : a; ar[j1] = sel ? a : bv;
                a = ai[j0]; bv = ai[j1];
                ai[j0] = sel ? bv : a; ai[j1] = sel ? a : bv;
            }
        }
    } else if constexpr (PT < 10) {
        constexpr int LM = 1 << (PT-4);
        if constexpr (PC < 4) {
            constexpr int CM = 1 << PC;
            #pragma unroll
            for (int j = 0; j < CHUNK; ++j) {
                if (j & CM) {
                    ar[j] = __shfl_xor(ar[j], LM, 64);
                    ai[j] = __shfl_xor(ai[j], LM, 64);
                }
            }
        } else {
            int sel = (tid >> (PC-4)) & 1;
            if (sel) {  // partner differs only in PT lane bit -> same sel
                #pragma unroll
                for (int j = 0; j < CHUNK; ++j) {
                    ar[j] = __shfl_xor(ar[j], LM, 64);
                    ai[j] = __shfl_xor(ai[j], LM, 64);
                }
            }
        }
    } else {
        constexpr int WM = 1 << (PT-4);
        int ptid = tid ^ WM;
        if constexpr (PC < 4) {
            constexpr int CM = 1 << PC;
            // exchange only the 8 ctrl==1 amps (half traffic)
            #pragma unroll
            for (int k = 0; k < 2; ++k) {
                float v[8];
                #pragma unroll
                for (int m = 0; m < 4; ++m) {
                    int i = 4*k + m;
                    int j = ((i >> PC) << (PC+1)) | (i & (CM-1)) | CM;
                    v[m] = ar[j]; v[4+m] = ai[j];
                }
                buf[k*NTHREADS + tid]     = make_float4(v[0],v[1],v[2],v[3]);
                buf[(k+2)*NTHREADS + tid] = make_float4(v[4],v[5],v[6],v[7]);
            }
            __syncthreads();
            #pragma unroll
            for (int k = 0; k < 2; ++k) {
                F4 pr = buf[k*NTHREADS + ptid];
                F4 pi = buf[(k+2)*NTHREADS + ptid];
                float prx[4] = {pr.x,pr.y,pr.z,pr.w};
                float pix[4] = {pi.x,pi.y,pi.z,pi.w};
                #pragma unroll
                for (int m = 0; m < 4; ++m) {
                    int i = 4*k + m;
                    int j = ((i >> PC) << (PC+1)) | (i & (CM-1)) | CM;
                    ar[j] = prx[m]; ai[j] = pix[m];
                }
            }
            __syncthreads();
        } else {
            // ctrl is a thread bit != PT: sel==1 threads swap whole chunk
            int sel = (tid >> (PC-4)) & 1;
            if (sel) {
                #pragma unroll
                for (int k = 0; k < 4; ++k) {
                    int j = 4*k;
                    buf[k*NTHREADS + tid]     = make_float4(ar[j],ar[j+1],ar[j+2],ar[j+3]);
                    buf[(k+4)*NTHREADS + tid] = make_float4(ai[j],ai[j+1],ai[j+2],ai[j+3]);
                }
            }
            __syncthreads();
            if (sel) {
                #pragma unroll
                for (int k = 0; k < 4; ++k) {
                    F4 pr = buf[k*NTHREADS + ptid];
                    F4 pi = buf[(k+4)*NTHREADS + ptid];
                    int j = 4*k;
                    ar[j]=pr.x; ar[j+1]=pr.y; ar[j+2]=pr.z; ar[j+3]=pr.w;
                    ai[j]=pi.x; ai[j+1]=pi.y; ai[j+2]=pi.z; ai[j+3]=pi.w;
                }
            }
            __syncthreads();
        }
    }
}

// ---- compile-time circuit drivers ----
template<int W>
__device__ __forceinline__ void do_rx(float (&ar)[CHUNK], float (&ai)[CHUNK],
                                      const float* __restrict__ xb, int tid, F4* buf) {
    float t = xb[W];
    float c = cosf(0.5f*t), s = sinf(0.5f*t);
    rx_gate<13-W>(ar, ai, c, s, tid, buf);
    if constexpr (W < NQ-1) do_rx<W+1>(ar, ai, xb, tid, buf);
}

template<int L, int W>
__device__ __forceinline__ void do_rots(float (&ar)[CHUNK], float (&ai)[CHUNK],
                                        const float* __restrict__ gm, int tid, F4* buf) {
    rot_gate<13-W>(ar, ai, gm + (L*NQ + W)*8, tid, buf);
    if constexpr (W < NQ-1) do_rots<L, W+1>(ar, ai, gm, tid, buf);
}

template<int L, int W>
__device__ __forceinline__ void do_cnots(float (&ar)[CHUNK], float (&ai)[CHUNK],
                                         int tid, F4* buf) {
    constexpr int R = (L % (NQ-1)) + 1;
    constexpr int TW = (W + R) % NQ;
    cnot_gate<13-W, 13-TW>(ar, ai, tid, buf);
    if constexpr (W < NQ-1) do_cnots<L, W+1>(ar, ai, tid, buf);
}

template<int L>
__device__ __forceinline__ void do_layer(float (&ar)[CHUNK], float (&ai)[CHUNK],
                                         const float* __restrict__ gm, int tid, F4* buf) {
    do_rots<L, 0>(ar, ai, gm, tid, buf);
    do_cnots<L, 0>(ar, ai, tid, buf);
    if constexpr (L < NL-1) do_layer<L+1>(ar, ai, gm, tid, buf);
}

__global__ __launch_bounds__(NTHREADS, 1) void qsim_kernel(
    const float* __restrict__ x,
    const float* __restrict__ gm,
    float* __restrict__ out)
{
    extern __shared__ F4 buf[];   // 8 * 1024 float4 = 128 KB exchange buffer
    const int tid = threadIdx.x;
    const int b = blockIdx.x;

    float ar[CHUNK], ai[CHUNK];
    #pragma unroll
    for (int j = 0; j < CHUNK; ++j) { ar[j] = 0.f; ai[j] = 0.f; }
    if (tid == 0) ar[0] = 1.f;

    do_rx<0>(ar, ai, x + b*NQ, tid, buf);
    do_layer<0>(ar, ai, gm, tid, buf);

    // <Z0>: amp bit 13 = tid bit 9 -> sign uniform per thread
    float acc = 0.f;
    #pragma unroll
    for (int j = 0; j < CHUNK; ++j) acc += ar[j]*ar[j] + ai[j]*ai[j];
    if (tid & 512) acc = -acc;
    #pragma unroll
    for (int off = 32; off > 0; off >>= 1) acc += __shfl_down(acc, off, 64);
    __syncthreads();
    float* f = (float*)buf;
    if ((tid & 63) == 0) f[tid >> 6] = acc;
    __syncthreads();
    if (tid == 0) {
        float s = 0.f;
        #pragma unroll
        for (int w = 0; w < NTHREADS/64; ++w) s += f[w];
        out[b] = s;
    }
}

extern "C" void kernel_launch(void* const* d_in, const int* in_sizes, int n_in,
                              void* d_out, int out_size, void* d_ws, size_t ws_size,
                              hipStream_t stream) {
    const float* x = (const float*)d_in[0];   // (1024, 14) float32
    const float* w = (const float*)d_in[1];   // (6, 14, 3) float32
    float* out = (float*)d_out;               // (1024,) float32
    float* gm = (float*)d_ws;                 // 84*8 floats of Rot matrices

    prep_kernel<<<1, 128, 0, stream>>>(w, gm);
    size_t smem = (size_t)8 * NTHREADS * sizeof(F4);  // 128 KB
    qsim_kernel<<<out_size, NTHREADS, smem, stream>>>(x, gm, out);
}